// Round 4
// baseline (302.363 us; speedup 1.0000x reference)
//
#include <hip/hip_runtime.h>
#include <stdint.h>

// ---------------------------------------------------------------------------
// MADE flow layer. I/O is FLOAT32 per the reference (R0-R2 read bf16 — that
// was the NaN bug: f32 mantissa halves as bf16 contain Inf/NaN patterns).
//   zp = z[:, perm]
//   h  = relu(zp @ (W1*M1) + b1)          GEMM1: 4096x1024x4096
//   res= h @ (W2*M2) + b2                 GEMM2: 4096x4096x2048
//   x[:, perm[i]] = zp[:,i]*exp(log_s)+mu ; log_det = sum(log_s)
// Masks analytic: M1[i][j] = (j%(D-1) >= i);  M2[h][o] = (o%D > h%(D-1))
// Compute core: bf16 MFMA (inputs cast f32->bf16 in preprocessing; error
// budget ~0.03 abs vs threshold 0.101).
//
// Workspace (80 MB peak if ws allows; else 64 MB with bf16 res):
//   [0,32M)   h     (B*H bf16)
//   [32,48M)  W2mT  (2D*H bf16)
//   [48,56M)  W1mT  (H*D bf16)   dead once GEMM2 starts
//   [56,64M)  zp    (B*D bf16)   dead once GEMM2 starts
//   [48,80M)  res   (B*2D f32)   overlays W1mT+zp
// ---------------------------------------------------------------------------

typedef __bf16  bf16x8 __attribute__((ext_vector_type(8)));
typedef float   f32x4  __attribute__((ext_vector_type(4)));
typedef ushort  u16x8  __attribute__((ext_vector_type(8)));

__device__ __forceinline__ ushort f2bf(float f) {
    union { float f; uint32_t u; } c; c.f = f;
    uint32_t u = c.u;
    if ((u & 0x7fffffffu) > 0x7f800000u) return (ushort)0x7fc0; // NaN
    uint32_t r = (u + 0x7fffu + ((u >> 16) & 1u)) >> 16;        // RNE
    return (ushort)r;
}
__device__ __forceinline__ float bf2f(ushort u) {
    union { uint32_t u; float f; } c; c.u = ((uint32_t)u) << 16; return c.f;
}

// ---------------------------------------------------------------------------
// Masked transpose + f32->bf16: WT[c][r] = mask(r,c) ? bf16(W[r][c]) : 0.
// W is RxC row-major float32.
// MODE 1: W1 (r=i in [0,D), c=j in [0,H)):  keep = (c % (Dv-1)) >= r
// MODE 2: W2 (r=h in [0,H), c=o in [0,2D)): keep = (c % Dv) > (r % (Dv-1))
// ---------------------------------------------------------------------------
template <int MODE>
__global__ __launch_bounds__(256) void mask_transpose(
    const float* __restrict__ W, ushort* __restrict__ WT, int R, int C, int Dv) {
    __shared__ ushort t[64][65];
    const int c0 = blockIdx.x * 64, r0 = blockIdx.y * 64;
    const int tx = threadIdx.x;   // 0..63
    const int ty = threadIdx.y;   // 0..3
    for (int rr = ty; rr < 64; rr += 4) {
        const int r = r0 + rr, c = c0 + tx;
        float v = W[(size_t)r * C + c];
        bool keep;
        if (MODE == 1) keep = (c % (Dv - 1)) >= r;
        else           keep = (c % Dv) > (r % (Dv - 1));
        t[rr][tx] = keep ? f2bf(v) : (ushort)0;
    }
    __syncthreads();
    for (int cc = ty; cc < 64; cc += 4) {
        WT[(size_t)(c0 + cc) * R + r0 + tx] = t[tx][cc];
    }
}

// zp[b][i] = bf16(z[b][perm[i]])  (z float32)
__global__ __launch_bounds__(256) void permute_rows(
    const float* __restrict__ z, const int* __restrict__ perm,
    ushort* __restrict__ zp, int D) {
    const int b = blockIdx.y;
    const int i = blockIdx.x * 256 + threadIdx.x;
    zp[(size_t)b * D + i] = f2bf(z[(size_t)b * D + perm[i]]);
}

// ---------------------------------------------------------------------------
// GEMM: C[M][N] = A[M][K] * Bt[N][K]^T + bias, A/Bt bf16 row-major, bias f32.
// 128x128 tile, BK=32, 256 threads = 4 waves, each wave 4x4 of 16x16x32 MFMA.
// Staging: per-lane ushort8 global load -> 16B LDS store (m93 structure).
// ---------------------------------------------------------------------------
template <int RELU, int OUT_F32>
__global__ __launch_bounds__(256) void gemm_bt(
    const ushort* __restrict__ A, const ushort* __restrict__ Bt,
    const float* __restrict__ bias, void* __restrict__ Cout,
    int M, int N, int K) {
    __shared__ __align__(16) ushort Alds[128 * 32];
    __shared__ __align__(16) ushort Blds[128 * 32];

    const int tid  = threadIdx.x;
    const int lane = tid & 63;
    const int w    = tid >> 6;
    const int m0   = blockIdx.y * 128;
    const int n0   = blockIdx.x * 128;
    const int wm   = (w & 1) * 64;
    const int wn   = (w >> 1) * 64;
    const int quad = lane >> 4;
    const int l16  = lane & 15;

    f32x4 acc[4][4];
#pragma unroll
    for (int i = 0; i < 4; i++)
#pragma unroll
        for (int j = 0; j < 4; j++) acc[i][j] = (f32x4)0.0f;

    // staging: tile = 128 rows x 32 k = 512 chunks of 16B (8 ushorts).
    // chunk c -> row c>>2, k-offset (c&3)*8. thread t handles chunks t, t+256.
    const int c0 = tid, c1 = tid + 256;
    const ushort* Ag0 = A + (size_t)(m0 + (c0 >> 2)) * K + (c0 & 3) * 8;
    const ushort* Ag1 = A + (size_t)(m0 + (c1 >> 2)) * K + (c1 & 3) * 8;
    const ushort* Bg0 = Bt + (size_t)(n0 + (c0 >> 2)) * K + (c0 & 3) * 8;
    const ushort* Bg1 = Bt + (size_t)(n0 + (c1 >> 2)) * K + (c1 & 3) * 8;

    const int aoff = (wm + l16) * 32 + quad * 8;
    const int boff = (wn + l16) * 32 + quad * 8;

    for (int kt = 0; kt < K; kt += 32) {
        u16x8 ra0 = *(const u16x8*)(Ag0 + kt);
        u16x8 ra1 = *(const u16x8*)(Ag1 + kt);
        u16x8 rb0 = *(const u16x8*)(Bg0 + kt);
        u16x8 rb1 = *(const u16x8*)(Bg1 + kt);

        __syncthreads();   // prior iter's LDS reads done before overwrite
        *(u16x8*)&Alds[c0 * 8] = ra0;
        *(u16x8*)&Alds[c1 * 8] = ra1;
        *(u16x8*)&Blds[c0 * 8] = rb0;
        *(u16x8*)&Blds[c1 * 8] = rb1;
        __syncthreads();   // staging visible to all waves

        bf16x8 af[4], bfr[4];
#pragma unroll
        for (int mi = 0; mi < 4; mi++)
            af[mi] = *(const bf16x8*)&Alds[aoff + mi * 16 * 32];
#pragma unroll
        for (int ni = 0; ni < 4; ni++)
            bfr[ni] = *(const bf16x8*)&Blds[boff + ni * 16 * 32];
#pragma unroll
        for (int mi = 0; mi < 4; mi++)
#pragma unroll
            for (int ni = 0; ni < 4; ni++)
                acc[mi][ni] = __builtin_amdgcn_mfma_f32_16x16x32_bf16(
                    af[mi], bfr[ni], acc[mi][ni], 0, 0, 0);
    }

    // epilogue: C/D layout col = lane&15, row = quad*4 + reg  (m89/m91 verified)
    float bv[4];
#pragma unroll
    for (int ni = 0; ni < 4; ni++) bv[ni] = bias[n0 + wn + ni * 16 + l16];
#pragma unroll
    for (int mi = 0; mi < 4; mi++) {
        const int row = m0 + wm + mi * 16 + quad * 4;
#pragma unroll
        for (int ni = 0; ni < 4; ni++) {
            const int col = n0 + wn + ni * 16 + l16;
#pragma unroll
            for (int r = 0; r < 4; r++) {
                float v = acc[mi][ni][r] + bv[ni];
                if (RELU) v = fmaxf(v, 0.0f);
                if (OUT_F32)
                    ((float*)Cout)[(size_t)(row + r) * N + col] = v;
                else
                    ((ushort*)Cout)[(size_t)(row + r) * N + col] = f2bf(v);
            }
        }
    }
}

// ---------------------------------------------------------------------------
// Finale: one block per batch row. All f32 I/O.
//   x_out[b][perm[i]] = z[b][perm[i]] * exp(log_s[b][i]) + mu[b][i]
//   log_det[b] = sum_i log_s[b][i]
// res is [B][2D]: mu = res[:, :D], log_s = res[:, D:]. RES_F32 picks dtype.
// ---------------------------------------------------------------------------
template <int RES_F32>
__global__ __launch_bounds__(256) void finale(
    const float* __restrict__ z, const int* __restrict__ perm,
    const void* __restrict__ res, float* __restrict__ out, int B, int D) {
    const int b   = blockIdx.x;
    const int tid = threadIdx.x;
    float lsum = 0.0f;
#pragma unroll
    for (int k = 0; k < 4; k++) {
        const int i  = tid + k * 256;
        float mu, ls;
        if (RES_F32) {
            const float* rrow = (const float*)res + (size_t)b * 2 * D;
            mu = rrow[i];
            ls = rrow[D + i];
        } else {
            const ushort* rrow = (const ushort*)res + (size_t)b * 2 * D;
            mu = bf2f(rrow[i]);
            ls = bf2f(rrow[D + i]);
        }
        ls = fminf(fmaxf(ls, -30.0f), 30.0f);   // lossless for sane data
        const int   pi = perm[i];
        const float zv = z[(size_t)b * D + pi];
        const float x  = zv * expf(ls) + mu;
        out[(size_t)b * D + pi] = x;
        lsum += ls;
    }
    // wave reduce (64 lanes) then cross-wave via LDS
#pragma unroll
    for (int o = 32; o > 0; o >>= 1) lsum += __shfl_down(lsum, o, 64);
    __shared__ float wsum[4];
    if ((tid & 63) == 0) wsum[tid >> 6] = lsum;
    __syncthreads();
    if (tid == 0) {
        float t = wsum[0] + wsum[1] + wsum[2] + wsum[3];
        out[(size_t)B * D + b] = t;
    }
}

// ---------------------------------------------------------------------------
extern "C" void kernel_launch(void* const* d_in, const int* in_sizes, int n_in,
                              void* d_out, int out_size, void* d_ws, size_t ws_size,
                              hipStream_t stream) {
    const float* z    = (const float*)d_in[0];
    const float* W1   = (const float*)d_in[1];
    const float* b1   = (const float*)d_in[2];
    const float* W2   = (const float*)d_in[3];
    const float* b2   = (const float*)d_in[4];
    const int*   perm = (const int*)d_in[5];
    float* out = (float*)d_out;
    char*  ws  = (char*)d_ws;

    const int D = in_sizes[5];          // 1024
    const int H = in_sizes[2];          // 4096
    const int B = in_sizes[0] / D;      // 4096

    const size_t off_h    = 0;
    const size_t off_W2mT = off_h    + (size_t)B * H * 2;       // 32 MB
    const size_t off_W1mT = off_W2mT + (size_t)2 * D * H * 2;   // 48 MB
    const size_t off_zp   = off_W1mT + (size_t)H * D * 2;       // 56 MB
    const size_t off_res  = off_W1mT;                           // 48 MB (reuse)
    const size_t res_f32_bytes = (size_t)B * 2 * D * 4;         // 32 MB
    const bool   res_f32 = (ws_size >= off_res + res_f32_bytes);

    ushort* h    = (ushort*)(ws + off_h);
    ushort* W2mT = (ushort*)(ws + off_W2mT);
    ushort* W1mT = (ushort*)(ws + off_W1mT);
    ushort* zp   = (ushort*)(ws + off_zp);
    void*   res  = (void*)(ws + off_res);

    mask_transpose<1><<<dim3(H / 64, D / 64), dim3(64, 4), 0, stream>>>(W1, W1mT, D, H, D);
    mask_transpose<2><<<dim3(2 * D / 64, H / 64), dim3(64, 4), 0, stream>>>(W2, W2mT, H, 2 * D, D);
    permute_rows<<<dim3(D / 256, B), 256, 0, stream>>>(z, perm, zp, D);

    // h = relu(zp @ W1m + b1)   [M=B, N=H, K=D]
    gemm_bt<1, 0><<<dim3(H / 128, B / 128), 256, 0, stream>>>(zp, W1mT, b1, h, B, H, D);

    // res = h @ W2m + b2        [M=B, N=2D, K=H]
    if (res_f32) {
        gemm_bt<0, 1><<<dim3(2 * D / 128, B / 128), 256, 0, stream>>>(h, W2mT, b2, res, B, 2 * D, H);
        finale<1><<<B, 256, 0, stream>>>(z, perm, res, out, B, D);
    } else {
        gemm_bt<0, 0><<<dim3(2 * D / 128, B / 128), 256, 0, stream>>>(h, W2mT, b2, res, B, 2 * D, H);
        finale<0><<<B, 256, 0, stream>>>(z, perm, res, out, B, D);
    }
}